// Round 6
// baseline (42.400 us; speedup 1.0000x reference)
//
#include <hip/hip_runtime.h>

// NormalComputer: out[b,:,i,j] = normalize(cross(up - down, right - left))
// Identity: sum of 4 reference cross products == cross(up-down, right-left);
// center cancels; idx input never read (clamped indices recomputed from i,j).
//
// R6: A/B isolating R4's confound — 8 px/thread (24 loads in flight) with
//     PLAIN float4 stores (R4's nt stores removed), 4096 blocks, 2 rows/block.
//     XCD slab swizzle kept (XCD x owns batch x). If this regresses vs R5's
//     35.0 us, the 4 px/thread + 8192-block shape was the winner and R5 is
//     ~87% of the float4-copy logical ceiling -> roofline.

#define HH 1024
#define WW 1024
#define BB 8
#define HW (HH * WW)

typedef float floatx4 __attribute__((ext_vector_type(4)));

__global__ __launch_bounds__(256)
void normal_kernel(const float* __restrict__ in, float* __restrict__ out) {
    // 4096 blocks; bijective chunked XCD swizzle: XCD x gets blocks [x*512,(x+1)*512)
    const int nb = (blockIdx.x & 7) * 512 + (blockIdx.x >> 3);
    const int b  = nb >> 9;                    // batch (== XCD index)
    const int rp = nb & 511;                   // row-pair within batch
    const int tid = threadIdx.x;
    const int i  = rp * 2 + (tid >> 7);        // 2 rows per block
    const int j0 = (tid & 127) << 3;           // 8 px per thread

    const int iu = (i > 0)      ? i - 1 : 0;
    const int id = (i < HH - 1) ? i + 1 : HH - 1;
    const int jL = (j0 > 0) ? j0 - 1 : 0;
    const int jR = (j0 + 8 < WW) ? j0 + 8 : WW - 1;

    const float* base = in + (size_t)b * 3 * HW;

    float ax[8][3], cx[8][3];
#pragma unroll
    for (int ch = 0; ch < 3; ++ch) {
        const float* pl = base + (size_t)ch * HW;
        const floatx4 u0 = *(const floatx4*)(pl + iu * WW + j0);
        const floatx4 u1 = *(const floatx4*)(pl + iu * WW + j0 + 4);
        const floatx4 d0 = *(const floatx4*)(pl + id * WW + j0);
        const floatx4 d1 = *(const floatx4*)(pl + id * WW + j0 + 4);
        const floatx4 m0 = *(const floatx4*)(pl + i  * WW + j0);
        const floatx4 m1 = *(const floatx4*)(pl + i  * WW + j0 + 4);
        const float lf  = pl[i * WW + jL];
        const float rt  = pl[i * WW + jR];

        const float u[8] = {u0.x,u0.y,u0.z,u0.w,u1.x,u1.y,u1.z,u1.w};
        const float d[8] = {d0.x,d0.y,d0.z,d0.w,d1.x,d1.y,d1.z,d1.w};
        const float m[8] = {m0.x,m0.y,m0.z,m0.w,m1.x,m1.y,m1.z,m1.w};

#pragma unroll
        for (int k = 0; k < 8; ++k) ax[k][ch] = u[k] - d[k];
        cx[0][ch] = m[1] - lf;
#pragma unroll
        for (int k = 1; k < 7; ++k) cx[k][ch] = m[k + 1] - m[k - 1];
        cx[7][ch] = rt - m[6];
    }

    floatx4 o[3][2];
#pragma unroll
    for (int k = 0; k < 8; ++k) {
        const float nx = ax[k][1] * cx[k][2] - ax[k][2] * cx[k][1];
        const float ny = ax[k][2] * cx[k][0] - ax[k][0] * cx[k][2];
        const float nz = ax[k][0] * cx[k][1] - ax[k][1] * cx[k][0];
        const float norm = sqrtf(nx * nx + ny * ny + nz * nz);
        const float inv  = 1.0f / fmaxf(norm, 1e-6f);
        o[0][k >> 2][k & 3] = nx * inv;
        o[1][k >> 2][k & 3] = ny * inv;
        o[2][k >> 2][k & 3] = nz * inv;
    }

    float* ob = out + (size_t)b * 3 * HW + i * WW + j0;
#pragma unroll
    for (int ch = 0; ch < 3; ++ch) {
        *(floatx4*)(ob + ch * HW)     = o[ch][0];
        *(floatx4*)(ob + ch * HW + 4) = o[ch][1];
    }
}

extern "C" void kernel_launch(void* const* d_in, const int* in_sizes, int n_in,
                              void* d_out, int out_size, void* d_ws, size_t ws_size,
                              hipStream_t stream) {
    const float* in = (const float*)d_in[0];
    float* out = (float*)d_out;
    const int grid = BB * HW / (256 * 8);     // 4096 blocks, 8 px/thread
    normal_kernel<<<grid, 256, 0, stream>>>(in, out);
}

// Round 7
// 33.368 us; speedup vs baseline: 1.2707x; 1.2707x over previous
//
#include <hip/hip_runtime.h>

// NormalComputer: out[b,:,i,j] = normalize(cross(up - down, right - left))
// Identity: sum of 4 reference cross products == cross(up-down, right-left);
// center cancels; idx input never read (clamped indices recomputed from i,j).
//
// R7: max-TLP shape (R1's 1 px/thread, 8M threads) + R5's bijective XCD slab
//     swizzle (XCD x owns batch-image x => vertical row sharing stays in one
//     per-XCD L2; FETCH 150->49 MB). R1 drove HBM at 4.96 TB/s with this
//     thread count; with the over-fetch fixed, 146 MB @ ~5 TB/s ~= 29 us.

#define HH 1024
#define WW 1024
#define BB 8
#define HW (HH * WW)

__global__ __launch_bounds__(256)
void normal_kernel(const float* __restrict__ in, float* __restrict__ out) {
    // 32768 blocks; bijective chunked XCD swizzle: XCD x gets blocks
    // [x*4096, (x+1)*4096) == batch-image x (4096 blocks of 256 px each).
    const int nb = (blockIdx.x & 7) * 4096 + (blockIdx.x >> 3);
    const int b = nb >> 12;                  // batch (== XCD index)
    const int p = ((nb & 4095) << 8) | threadIdx.x;   // pixel within image
    const int i = p >> 10;                   // row
    const int j = p & (WW - 1);              // col

    const int iu = (i > 0)      ? i - 1 : 0;
    const int id = (i < HH - 1) ? i + 1 : HH - 1;
    const int jl = (j > 0)      ? j - 1 : 0;
    const int jr = (j < WW - 1) ? j + 1 : WW - 1;

    const float* base = in + (size_t)b * 3 * HW;

    float a[3], c[3];
#pragma unroll
    for (int ch = 0; ch < 3; ++ch) {
        const float* pl = base + (size_t)ch * HW;
        const float up = pl[iu * WW + j];
        const float dn = pl[id * WW + j];
        const float rt = pl[i * WW + jr];
        const float lf = pl[i * WW + jl];
        a[ch] = up - dn;   // d0 - d2
        c[ch] = rt - lf;   // d1 - d3
    }

    const float nx = a[1] * c[2] - a[2] * c[1];
    const float ny = a[2] * c[0] - a[0] * c[2];
    const float nz = a[0] * c[1] - a[1] * c[0];

    const float norm = sqrtf(nx * nx + ny * ny + nz * nz);
    const float inv  = 1.0f / fmaxf(norm, 1e-6f);

    float* ob = out + (size_t)b * 3 * HW + p;
    ob[0]        = nx * inv;
    ob[HW]       = ny * inv;
    ob[2 * HW]   = nz * inv;
}

extern "C" void kernel_launch(void* const* d_in, const int* in_sizes, int n_in,
                              void* d_out, int out_size, void* d_ws, size_t ws_size,
                              hipStream_t stream) {
    const float* in = (const float*)d_in[0];
    float* out = (float*)d_out;
    const int total = BB * HW;               // 8M threads
    const int block = 256;
    const int grid = total / block;          // 32768 blocks
    normal_kernel<<<grid, block, 0, stream>>>(in, out);
}